// Round 6
// baseline (97.393 us; speedup 1.0000x reference)
//
#include <hip/hip_runtime.h>
#include <hip/hip_bf16.h>

// VarFlowLoss on MI355X (gfx950) — round 6 (round-5 structure, halo-init bug fixed)
//   k_weights : W_att -> WT1 [9][64][256] bf16 ; W_post -> WT2 [9][16][64] bf16 (od padded)
//   k_gemm1   : fused transpose+conv GEMM. BM=512, 8 waves. FULLY double-buffered
//               (A reg-staged fp32->bf16 + B via source-swizzled glds), ONE barrier per
//               chunk, loads issued at chunk top so the 9-tap MFMA phase covers latency.
//   k_borders : out=0 ; slab-coalesced patch border log-sums -> S
//   k_gemm2   : post conv + fused smooth-L1 loss (swizzled A/B, dbuf A via glds)

typedef __attribute__((ext_vector_type(4))) float f32x4;
typedef __attribute__((ext_vector_type(8))) short s16x8;

#define DEVFN __device__ __forceinline__

DEVFN float bf2f(unsigned short u){
  unsigned int x = ((unsigned int)u) << 16;
  float f; __builtin_memcpy(&f, &x, 4); return f;
}
DEVFN unsigned short f2bf(float f){
  unsigned int x; __builtin_memcpy(&x, &f, 4);
  x += 0x7fffu + ((x >> 16) & 1u);   // RNE
  return (unsigned short)(x >> 16);
}

#define ASYNC16(gp, lp) __builtin_amdgcn_global_load_lds( \
    (const __attribute__((address_space(1))) unsigned int*)(gp), \
    (__attribute__((address_space(3))) unsigned int*)(lp), 16, 0, 0)

// ---------------- weights transform ----------------
__global__ void k_weights(const float* __restrict__ Watt, const float* __restrict__ Wpost,
                          unsigned short* __restrict__ WT1, unsigned short* __restrict__ WT2){
  const int t = blockIdx.x * 256 + threadIdx.x;
  const int n1 = 9 * 64 * 256;
  if (t < n1){
    const int tap = t / (64 * 256);
    const int rem = t % (64 * 256);
    const int oc = rem / 256, ic = rem % 256;
    WT1[t] = f2bf(Watt[(oc * 256 + ic) * 9 + tap]);
  }
  const int n2 = 9 * 16 * 64;
  if (t < n2){
    const int tap = t / (16 * 64);
    const int rem = t % (16 * 64);
    const int od = rem / 64, ic = rem % 64;
    const float v = (od < 10) ? Wpost[(od * 64 + ic) * 9 + tap] : 0.0f;
    WT2[t] = f2bf(v);
  }
}

// ---------------- borders: out=0 + patch border log-sums ----------------
__global__ void k_borders(const float* __restrict__ gts, float* __restrict__ S,
                          float* __restrict__ out){
  const int bid = blockIdx.x, tid = threadIdx.x;
  if (bid == 0 && tid == 0) *out = 0.0f;
  __shared__ float slab[4096];
  const int rel = bid;                  // = b*64 + py
  const float* gp = gts + (size_t)rel * 4096;
#pragma unroll
  for (int it = 0; it < 4; ++it){
    const int id = it * 256 + tid;
    *(f32x4*)&slab[id * 4] = *(const f32x4*)&gp[id * 4];
  }
  __syncthreads();
  const int px = tid & 63, border = tid >> 6;   // border wave-uniform
  float s = 0.0f;
#pragma unroll
  for (int i = 0; i < 8; ++i){
    float v;
    if (border == 0)      v = slab[px * 8 + i];
    else if (border == 1) v = slab[7 * 512 + px * 8 + i];
    else if (border == 2) v = slab[i * 512 + px * 8];
    else                  v = slab[i * 512 + px * 8 + 7];
    v = ((v > 0.1f) && (v < 80.0f)) ? v : 0.0f;
    s += __logf(v + 1e-6f);
  }
  S[((size_t)rel * 64 + px) * 4 + border] = s;
}

// ---------------- GEMM1: fused transpose + att conv + sigmoid * depth ----------------
// 256 blocks x 512 threads (8 waves). BM=512, BK=32, 8 chunks.
// A: dbuf [2][10 yy][68 xp][32 ic], zero columns xp=0,65; reg-staged fp32->bf16.
// B: dbuf [2][576 rows][32 ic] via source-swizzled global_load_lds.
// ONE __syncthreads per chunk; loads for c+1 issued before the compute phase of c.
__global__ __launch_bounds__(512, 2) void k_gemm1(
    const float* __restrict__ feat,             // NCHW fp32 [B][256][64][64]
    const unsigned short* __restrict__ WT1,     // [9][64][256]
    const float* __restrict__ batt,
    const float* __restrict__ depth,            // NCHW fp32 [B][64][64][64]
    unsigned short* __restrict__ adT)           // [B*4096][64]
{
  __shared__ unsigned short As[2][680 * 32];   // 2 x 42.5 KB, XOR-swizzled
  __shared__ unsigned short Bs[2][576 * 32];   // 2 x 36 KB, XOR-swizzled via source
  const int t = threadIdx.x;
  const int l = t & 63, w = t >> 6;
  const int b = blockIdx.x >> 3, ytile = blockIdx.x & 7;
  const int y0 = ytile * 8;
  const int fr = l & 15, g = l >> 4;
  const int x = t & 63, seg = t >> 6;

  f32x4 acc[4][4];
#pragma unroll
  for (int i = 0; i < 4; ++i)
#pragma unroll
    for (int j = 0; j < 4; ++j)
#pragma unroll
      for (int q = 0; q < 4; ++q) acc[i][j][q] = 0.0f;

  // zero the x-halo columns (xp=0,65) once, in BOTH buffers.
  // 160 threads = 2 buffers x 10 yy x 8 (xp-parity x 4 slots). Zero is swizzle-invariant.
  if (t < 160){
    const int d = t / 80;
    const int r = t - d * 80;
    const int yy = r >> 3, k = r & 7;
    const int xp = (k & 1) ? 65 : 0;
    s16x8 z = {0,0,0,0,0,0,0,0};
    *(s16x8*)&As[d][(yy * 68 + xp) * 32 + (k >> 1) * 8] = z;
  }

  auto stageB = [&](int c, int d){
#pragma unroll
    for (int it = 0; it < 5; ++it){
      const int idx = it * 512 + t;
      if (idx < 2304){
        const int row = idx >> 2;
        const int sg = (idx & 3) ^ ((row >> 1) & 3);   // source-slot swizzle
        ASYNC16(WT1 + (size_t)row * 256 + c * 32 + sg * 8, &Bs[d][(size_t)idx * 8]);
      }
    }
  };
  auto loadA = [&](int c, float* rr){
#pragma unroll
    for (int j = 0; j < 5; ++j){
      const int idx = seg + j * 8;                 // 0..39
      const int yy = idx >> 2, icg = idx & 3;
      const int yr = y0 - 1 + yy;
      if (yr >= 0 && yr < 64){
        const float* gp = feat + ((size_t)(b * 256 + c * 32 + icg * 8)) * 4096
                               + (size_t)yr * 64 + x;
#pragma unroll
        for (int e = 0; e < 8; ++e) rr[j * 8 + e] = gp[(size_t)e * 4096];
      } else {
#pragma unroll
        for (int e = 0; e < 8; ++e) rr[j * 8 + e] = 0.0f;
      }
    }
  };
  auto cvtA = [&](const float* rr, s16x8* vA){
#pragma unroll
    for (int j = 0; j < 5; ++j)
#pragma unroll
      for (int e = 0; e < 8; ++e) vA[j][e] = (short)f2bf(rr[j * 8 + e]);
  };
  auto writeA = [&](int d, const s16x8* vA){
    const int xp = x + 1;
    const int sx = (xp >> 1) & 3;
#pragma unroll
    for (int j = 0; j < 5; ++j){
      const int idx = seg + j * 8;
      const int yy = idx >> 2, icg = idx & 3;
      *(s16x8*)&As[d][(yy * 68 + xp) * 32 + ((icg ^ sx) * 8)] = vA[j];
    }
  };
  auto compute = [&](const unsigned short* Ab, const unsigned short* Bb){
    const int slotB = (g ^ ((fr >> 1) & 3)) * 8;
    for (int tap = 0; tap < 9; ++tap){
      const int dy = tap / 3 - 1, dxp = tap % 3;     // dx+1
      const int r = fr + dxp;                        // xp of fragment base
      const int slotA = (g ^ ((r >> 1) & 3)) * 8;    // (i*16 term is 0 mod 4 after >>1)
      const int rowb = ((w + dy + 1) * 68 + r) * 32 + slotA;
      s16x8 af[4], bfr[4];
#pragma unroll
      for (int i = 0; i < 4; ++i) af[i] = *(const s16x8*)&Ab[rowb + i * 512];
#pragma unroll
      for (int j = 0; j < 4; ++j)
        bfr[j] = *(const s16x8*)&Bb[(tap * 64 + j * 16 + fr) * 32 + slotB];
#pragma unroll
      for (int i = 0; i < 4; ++i)
#pragma unroll
        for (int j = 0; j < 4; ++j)
          acc[i][j] = __builtin_amdgcn_mfma_f32_16x16x32_bf16(af[i], bfr[j], acc[i][j], 0, 0, 0);
    }
  };

  // prologue: chunk 0 into buffer 0
  float rr[40]; s16x8 vA[5];
  loadA(0, rr);
  stageB(0, 0);
  cvtA(rr, vA);
  writeA(0, vA);
  __syncthreads();

  for (int c = 0; c < 8; ++c){
    const int cur = c & 1;
    if (c < 7){
      loadA(c + 1, rr);                // A-reg loads first (counted vmcnt at cvtA)
      stageB(c + 1, cur ^ 1);          // B glds second (drained only at barrier)
    }
    compute(As[cur], Bs[cur]);         // 72 ds_read + 144 MFMA cover the latency
    if (c < 7){
      cvtA(rr, vA);
      writeA(cur ^ 1, vA);
    }
    __syncthreads();
  }

  // epilogue: att = sigmoid(acc + b); adT = att * depth
  const int y = y0 + w;
#pragma unroll
  for (int j = 0; j < 4; ++j){
    const int oc = j * 16 + fr;
    const float bb = batt[oc];
    const float* dpt = depth + ((size_t)(b * 64 + oc)) * 4096 + (size_t)y * 64;
    unsigned short* op = adT + ((size_t)(b * 4096 + y * 64)) * 64 + oc;
#pragma unroll
    for (int i = 0; i < 4; ++i){
#pragma unroll
      for (int q = 0; q < 4; ++q){
        const int xo = i * 16 + g * 4 + q;
        const float v = acc[i][j][q] + bb;
        const float att = 1.0f / (1.0f + __expf(-v));
        op[(size_t)xo * 64] = f2bf(att * dpt[xo]);
      }
    }
  }
}

// ---------------- GEMM2: post conv + fused smooth-L1 loss ----------------
DEVFN float sel4(f32x4 v, int i){
  const float ab = (i & 1) ? v[1] : v[0];
  const float cd = (i & 1) ? v[3] : v[2];
  return (i & 2) ? cd : ab;
}

__global__ __launch_bounds__(512, 2) void k_gemm2(
    const unsigned short* __restrict__ adT,     // [B*4096][64]
    const unsigned short* __restrict__ WT2,     // [9][16][64]
    const float* __restrict__ bpost,
    const f32x4* __restrict__ S,                // [B*4096] {Sn,Ss,Sw,Se}
    float* __restrict__ out)
{
  __shared__ unsigned short As[2][20480];   // 80 KB, source-swizzled
  __shared__ unsigned short Bs[9216];       // full B resident (18 KB), source-swizzled
  __shared__ float ps[8];
  const int t = threadIdx.x;
  const int l = t & 63, w = t >> 6;
  const int b = blockIdx.x >> 3, ytile = blockIdx.x & 7;
  const int y0 = ytile * 8;
  const int fr = l & 15, g = l >> 4;

  f32x4 acc[4];
#pragma unroll
  for (int i = 0; i < 4; ++i)
#pragma unroll
    for (int q = 0; q < 4; ++q) acc[i][q] = 0.0f;

  auto stageA = [&](int c, int d){
#pragma unroll
    for (int it2 = 0; it2 < 5; ++it2){
      const int it = it2 * 2 + (t >> 8);
      const int yy = y0 - 1 + it;
      const int xx = (t >> 2) & 63, icg = t & 3;
      unsigned short* lp = &As[d][(it * 64 + xx) * 32 + icg * 8];
      if (yy >= 0 && yy < 64){
        const int sg = icg ^ ((xx >> 1) & 3);        // source-slot swizzle
        const unsigned short* gp = adT
            + ((size_t)(b * 4096 + yy * 64 + xx)) * 64 + c * 32 + sg * 8;
        ASYNC16(gp, lp);
      } else {
        s16x8 z = {0,0,0,0,0,0,0,0};
        *(s16x8*)lp = z;
      }
    }
  };
  // stage all of B once (144 rows x 128B), 16B slots XOR'd by row&7
#pragma unroll
  for (int it = 0; it < 3; ++it){
    const int idx = it * 512 + t;
    if (idx < 1152){
      const int row = idx >> 3, p = idx & 7;
      const int sg = p ^ (row & 7);
      ASYNC16(WT2 + (size_t)row * 64 + sg * 8, Bs + (size_t)idx * 8);
    }
  }
  stageA(0, 0);
  __syncthreads();

  for (int c = 0; c < 2; ++c){
    if (c == 0) stageA(1, 1);
    const unsigned short* Ab = As[c];
    const int pB = ((c * 4 + g) ^ (fr & 7)) * 8;
    for (int tap = 0; tap < 9; ++tap){
      const int dy = tap / 3 - 1, dx = tap % 3 - 1;
      s16x8 af[4];
#pragma unroll
      for (int i = 0; i < 4; ++i){
        const int xv = i * 16 + fr + dx;
        const bool valid = (xv >= 0) && (xv < 64);
        const int xw = valid ? xv : 0;
        const int slot = (g ^ ((xw >> 1) & 3)) * 8;
        s16x8 v = *(const s16x8*)&Ab[((w + dy + 1) * 64 + xw) * 32 + slot];
        s16x8 z = {0,0,0,0,0,0,0,0};
        af[i] = valid ? v : z;
      }
      const s16x8 bfr = *(const s16x8*)&Bs[(tap * 16 + fr) * 64 + pB];
#pragma unroll
      for (int i = 0; i < 4; ++i)
        acc[i] = __builtin_amdgcn_mfma_f32_16x16x32_bf16(af[i], bfr, acc[i], 0, 0, 0);
    }
    __syncthreads();
  }

  // fused loss epilogue
  const unsigned aPack = (3u<<0)|(1u<<2)|(3u<<4)|(1u<<6)|(2u<<8)|(0u<<10)|(1u<<12)|(3u<<14)|(0u<<16)|(2u<<18);
  const unsigned bPack = (2u<<0)|(0u<<2)|(3u<<4)|(1u<<6)|(2u<<8)|(0u<<10)|(1u<<12)|(3u<<14)|(0u<<16)|(2u<<18);
  float lsum = 0.0f;
  const int y = y0 + w;
  if (fr < 10){
    const int od = fr;
    const int ai = (aPack >> (2 * od)) & 3;
    const int bi = (bPack >> (2 * od)) & 3;
    const bool xshift = (od & 1) == 0;
    const float bp = bpost[od];
#pragma unroll
    for (int i = 0; i < 4; ++i){
#pragma unroll
      for (int q = 0; q < 4; ++q){
        const int xo = i * 16 + g * 4 + q;
        const size_t gm = (size_t)b * 4096 + (size_t)y * 64 + xo;
        const f32x4 sa = S[gm];
        const bool nb = xshift ? (xo < 63) : (y < 63);
        const size_t ga = xshift ? (nb ? gm + 1 : gm) : (nb ? gm + 64 : gm);
        const f32x4 sbv = S[ga];
        const float sbf = nb ? sel4(sbv, bi) : 0.0f;
        const float flow = (sel4(sa, ai) - sbf) * 0.125f;
        const float dv = acc[i][q] + bp - flow;
        const float adv = fabsf(dv);
        lsum += (adv < 0.01f) ? (50.0f * dv * dv) : (adv - 0.005f);
      }
    }
  }
#pragma unroll
  for (int off = 32; off > 0; off >>= 1) lsum += __shfl_down(lsum, off);
  if (l == 0) ps[w] = lsum;
  __syncthreads();
  if (t == 0){
    float s = 0.0f;
#pragma unroll
    for (int i = 0; i < 8; ++i) s += ps[i];
    atomicAdd(out, s * (1.0f / 1310720.0f));
  }
}

// ---------------- launch ----------------
extern "C" void kernel_launch(void* const* d_in, const int* in_sizes, int n_in,
                              void* d_out, int out_size, void* d_ws, size_t ws_size,
                              hipStream_t stream){
  const float* feat  = (const float*)d_in[0];
  const float* depth = (const float*)d_in[1];
  const float* gts   = (const float*)d_in[2];
  const float* Watt  = (const float*)d_in[3];
  const float* batt  = (const float*)d_in[4];
  const float* Wpost = (const float*)d_in[5];
  const float* bpost = (const float*)d_in[6];
  float* out = (float*)d_out;
  char* ws = (char*)d_ws;

  unsigned short* adT = (unsigned short*)ws;                       // 16777216 B
  unsigned short* WT1 = (unsigned short*)(ws + 16777216);          // 294912 B
  unsigned short* WT2 = (unsigned short*)(ws + 16777216 + 294912); // 18432 B
  float*          S   = (float*)(ws + 16777216 + 294912 + 18432);  // 2097152 B

  k_weights<<<576, 256, 0, stream>>>(Watt, Wpost, WT1, WT2);
  k_gemm1<<<256, 512, 0, stream>>>(feat, WT1, batt, depth, adT);
  k_borders<<<2048, 256, 0, stream>>>(gts, S, out);
  k_gemm2<<<256, 512, 0, stream>>>(adT, WT2, bpost, (const f32x4*)S, out);
}

// Round 7
// 90.163 us; speedup vs baseline: 1.0802x; 1.0802x over previous
//
#include <hip/hip_runtime.h>
#include <hip/hip_bf16.h>

// VarFlowLoss on MI355X (gfx950) — round 7
// Key change vs r6: gemm1 regime fix — BM=256, 256 threads, 62 KB LDS -> 2 blocks/CU
// (16 waves/CU), simple 2-barrier chunk loop; cross-block overlap hides stage stalls
// (m97/m114 pattern) instead of intra-block pipelining at 1 block/CU.

typedef __attribute__((ext_vector_type(4))) float f32x4;
typedef __attribute__((ext_vector_type(8))) short s16x8;

#define DEVFN __device__ __forceinline__

DEVFN float bf2f(unsigned short u){
  unsigned int x = ((unsigned int)u) << 16;
  float f; __builtin_memcpy(&f, &x, 4); return f;
}
DEVFN unsigned short f2bf(float f){
  unsigned int x; __builtin_memcpy(&x, &f, 4);
  x += 0x7fffu + ((x >> 16) & 1u);   // RNE
  return (unsigned short)(x >> 16);
}

#define ASYNC16(gp, lp) __builtin_amdgcn_global_load_lds( \
    (const __attribute__((address_space(1))) unsigned int*)(gp), \
    (__attribute__((address_space(3))) unsigned int*)(lp), 16, 0, 0)

// ---------------- weights transform ----------------
__global__ void k_weights(const float* __restrict__ Watt, const float* __restrict__ Wpost,
                          unsigned short* __restrict__ WT1, unsigned short* __restrict__ WT2){
  const int t = blockIdx.x * 256 + threadIdx.x;
  const int n1 = 9 * 64 * 256;
  if (t < n1){
    const int tap = t / (64 * 256);
    const int rem = t % (64 * 256);
    const int oc = rem / 256, ic = rem % 256;
    WT1[t] = f2bf(Watt[(oc * 256 + ic) * 9 + tap]);
  }
  const int n2 = 9 * 16 * 64;
  if (t < n2){
    const int tap = t / (16 * 64);
    const int rem = t % (16 * 64);
    const int od = rem / 64, ic = rem % 64;
    const float v = (od < 10) ? Wpost[(od * 64 + ic) * 9 + tap] : 0.0f;
    WT2[t] = f2bf(v);
  }
}

// ---------------- borders: out=0 + patch border log-sums ----------------
__global__ void k_borders(const float* __restrict__ gts, float* __restrict__ S,
                          float* __restrict__ out){
  const int bid = blockIdx.x, tid = threadIdx.x;
  if (bid == 0 && tid == 0) *out = 0.0f;
  __shared__ float slab[4096];
  const int rel = bid;                  // = b*64 + py
  const float* gp = gts + (size_t)rel * 4096;
#pragma unroll
  for (int it = 0; it < 4; ++it){
    const int id = it * 256 + tid;
    *(f32x4*)&slab[id * 4] = *(const f32x4*)&gp[id * 4];
  }
  __syncthreads();
  const int px = tid & 63, border = tid >> 6;   // border wave-uniform
  float s = 0.0f;
#pragma unroll
  for (int i = 0; i < 8; ++i){
    float v;
    if (border == 0)      v = slab[px * 8 + i];
    else if (border == 1) v = slab[7 * 512 + px * 8 + i];
    else if (border == 2) v = slab[i * 512 + px * 8];
    else                  v = slab[i * 512 + px * 8 + 7];
    v = ((v > 0.1f) && (v < 80.0f)) ? v : 0.0f;
    s += __logf(v + 1e-6f);
  }
  S[((size_t)rel * 64 + px) * 4 + border] = s;
}

// ---------------- GEMM1: fused transpose + att conv + sigmoid * depth ----------------
// 512 blocks x 256 threads (4 waves). BM=256 (4 y-rows), BK=32, 8 chunks.
// A: single [6 yy][66 xp][32 ic] bf16, zero cols xp=0,65, reg-staged fp32->bf16, swizzled.
// B: single [576 rows][32 ic] via source-swizzled global_load_lds.
// 2 barriers per chunk; cross-block overlap (2 blocks/CU) hides the stage stalls.
__global__ __launch_bounds__(256, 2) void k_gemm1(
    const float* __restrict__ feat,             // NCHW fp32 [B][256][64][64]
    const unsigned short* __restrict__ WT1,     // [9][64][256]
    const float* __restrict__ batt,
    const float* __restrict__ depth,            // NCHW fp32 [B][64][64][64]
    unsigned short* __restrict__ adT)           // [B*4096][64]
{
  __shared__ unsigned short As[6 * 66 * 32];   // 25344 B, XOR-swizzled
  __shared__ unsigned short Bs[576 * 32];      // 36864 B, XOR-swizzled via source
  const int t = threadIdx.x;
  const int l = t & 63, w = t >> 6;            // w: wave index (0..3) = y-local = A ic-group
  const int b = blockIdx.x >> 4, ytile = blockIdx.x & 15;
  const int y0 = ytile * 4;
  const int fr = l & 15, g = l >> 4;
  const int x = l;                             // 0..63

  f32x4 acc[4][4];
#pragma unroll
  for (int i = 0; i < 4; ++i)
#pragma unroll
    for (int j = 0; j < 4; ++j)
#pragma unroll
      for (int q = 0; q < 4; ++q) acc[i][j][q] = 0.0f;

  // zero the x-halo columns (xp=0,65) once: 48 threads = 6 yy x 2 xp x 4 slots
  if (t < 48){
    const int yy = t >> 3, k = t & 7;
    const int xp = (k & 1) ? 65 : 0;
    s16x8 z = {0,0,0,0,0,0,0,0};
    *(s16x8*)&As[(yy * 66 + xp) * 32 + (k >> 1) * 8] = z;
  }

  const int xp = x + 1;
  const int sx = (xp >> 1) & 3;
  const int slotB = (g ^ ((fr >> 1) & 3)) * 8;

  for (int c = 0; c < 8; ++c){
    // ---- stage phase ----
    float rr[48];
#pragma unroll
    for (int j = 0; j < 6; ++j){               // j = yy
      const int yr = y0 - 1 + j;
      if (yr >= 0 && yr < 64){
        const float* gp = feat + ((size_t)(b * 256 + c * 32 + w * 8)) * 4096
                               + (size_t)yr * 64 + x;
#pragma unroll
        for (int e = 0; e < 8; ++e) rr[j * 8 + e] = gp[(size_t)e * 4096];
      } else {
#pragma unroll
        for (int e = 0; e < 8; ++e) rr[j * 8 + e] = 0.0f;
      }
    }
#pragma unroll
    for (int it = 0; it < 9; ++it){            // B: 2304 16B chunks / 256 threads
      const int idx = it * 256 + t;
      const int row = idx >> 2;
      const int sg = (idx & 3) ^ ((row >> 1) & 3);   // source-slot swizzle
      ASYNC16(WT1 + (size_t)row * 256 + c * 32 + sg * 8, &Bs[(size_t)idx * 8]);
    }
#pragma unroll
    for (int j = 0; j < 6; ++j){
      s16x8 v;
#pragma unroll
      for (int e = 0; e < 8; ++e) v[e] = (short)f2bf(rr[j * 8 + e]);
      *(s16x8*)&As[(j * 66 + xp) * 32 + ((w ^ sx) * 8)] = v;
    }
    __syncthreads();                           // LDS ready (glds drained here)

    // ---- compute phase ----
    for (int tap = 0; tap < 9; ++tap){
      const int dy = tap / 3 - 1, dxp = tap % 3;     // dx+1
      const int r = fr + dxp;                        // xp of fragment base
      const int slotA = (g ^ ((r >> 1) & 3)) * 8;    // +16 in xp keeps (>>1)&3 invariant
      const int rowb = ((w + dy + 1) * 66 + r) * 32 + slotA;
      s16x8 af[4], bfr[4];
#pragma unroll
      for (int i = 0; i < 4; ++i) af[i] = *(const s16x8*)&As[rowb + i * 512];
#pragma unroll
      for (int j = 0; j < 4; ++j)
        bfr[j] = *(const s16x8*)&Bs[(tap * 64 + j * 16 + fr) * 32 + slotB];
#pragma unroll
      for (int i = 0; i < 4; ++i)
#pragma unroll
        for (int j = 0; j < 4; ++j)
          acc[i][j] = __builtin_amdgcn_mfma_f32_16x16x32_bf16(af[i], bfr[j], acc[i][j], 0, 0, 0);
    }
    __syncthreads();                           // readers done before next chunk's writes
  }

  // epilogue: att = sigmoid(acc + b); adT = att * depth
  const int y = y0 + w;
#pragma unroll
  for (int j = 0; j < 4; ++j){
    const int oc = j * 16 + fr;
    const float bb = batt[oc];
    const float* dpt = depth + ((size_t)(b * 64 + oc)) * 4096 + (size_t)y * 64;
    unsigned short* op = adT + ((size_t)(b * 4096 + y * 64)) * 64 + oc;
#pragma unroll
    for (int i = 0; i < 4; ++i){
#pragma unroll
      for (int q = 0; q < 4; ++q){
        const int xo = i * 16 + g * 4 + q;
        const float v = acc[i][j][q] + bb;
        const float att = 1.0f / (1.0f + __expf(-v));
        op[(size_t)xo * 64] = f2bf(att * dpt[xo]);
      }
    }
  }
}

// ---------------- GEMM2: post conv + fused smooth-L1 loss ----------------
DEVFN float sel4(f32x4 v, int i){
  const float ab = (i & 1) ? v[1] : v[0];
  const float cd = (i & 1) ? v[3] : v[2];
  return (i & 2) ? cd : ab;
}

__global__ __launch_bounds__(512, 2) void k_gemm2(
    const unsigned short* __restrict__ adT,     // [B*4096][64]
    const unsigned short* __restrict__ WT2,     // [9][16][64]
    const float* __restrict__ bpost,
    const f32x4* __restrict__ S,                // [B*4096] {Sn,Ss,Sw,Se}
    float* __restrict__ out)
{
  __shared__ unsigned short As[2][20480];   // 80 KB, source-swizzled
  __shared__ unsigned short Bs[9216];       // full B resident (18 KB), source-swizzled
  __shared__ float ps[8];
  const int t = threadIdx.x;
  const int l = t & 63, w = t >> 6;
  const int b = blockIdx.x >> 3, ytile = blockIdx.x & 7;
  const int y0 = ytile * 8;
  const int fr = l & 15, g = l >> 4;

  f32x4 acc[4];
#pragma unroll
  for (int i = 0; i < 4; ++i)
#pragma unroll
    for (int q = 0; q < 4; ++q) acc[i][q] = 0.0f;

  auto stageA = [&](int c, int d){
#pragma unroll
    for (int it2 = 0; it2 < 5; ++it2){
      const int it = it2 * 2 + (t >> 8);
      const int yy = y0 - 1 + it;
      const int xx = (t >> 2) & 63, icg = t & 3;
      unsigned short* lp = &As[d][(it * 64 + xx) * 32 + icg * 8];
      if (yy >= 0 && yy < 64){
        const int sg = icg ^ ((xx >> 1) & 3);        // source-slot swizzle
        const unsigned short* gp = adT
            + ((size_t)(b * 4096 + yy * 64 + xx)) * 64 + c * 32 + sg * 8;
        ASYNC16(gp, lp);
      } else {
        s16x8 z = {0,0,0,0,0,0,0,0};
        *(s16x8*)lp = z;
      }
    }
  };
  // stage all of B once (144 rows x 128B), 16B slots XOR'd by row&7
#pragma unroll
  for (int it = 0; it < 3; ++it){
    const int idx = it * 512 + t;
    if (idx < 1152){
      const int row = idx >> 3, p = idx & 7;
      const int sg = p ^ (row & 7);
      ASYNC16(WT2 + (size_t)row * 64 + sg * 8, Bs + (size_t)idx * 8);
    }
  }
  stageA(0, 0);
  __syncthreads();

  for (int c = 0; c < 2; ++c){
    if (c == 0) stageA(1, 1);
    const unsigned short* Ab = As[c];
    const int pB = ((c * 4 + g) ^ (fr & 7)) * 8;
    for (int tap = 0; tap < 9; ++tap){
      const int dy = tap / 3 - 1, dx = tap % 3 - 1;
      s16x8 af[4];
#pragma unroll
      for (int i = 0; i < 4; ++i){
        const int xv = i * 16 + fr + dx;
        const bool valid = (xv >= 0) && (xv < 64);
        const int xw = valid ? xv : 0;
        const int slot = (g ^ ((xw >> 1) & 3)) * 8;
        s16x8 v = *(const s16x8*)&Ab[((w + dy + 1) * 64 + xw) * 32 + slot];
        s16x8 z = {0,0,0,0,0,0,0,0};
        af[i] = valid ? v : z;
      }
      const s16x8 bfr = *(const s16x8*)&Bs[(tap * 16 + fr) * 64 + pB];
#pragma unroll
      for (int i = 0; i < 4; ++i)
        acc[i] = __builtin_amdgcn_mfma_f32_16x16x32_bf16(af[i], bfr, acc[i], 0, 0, 0);
    }
    __syncthreads();
  }

  // fused loss epilogue
  const unsigned aPack = (3u<<0)|(1u<<2)|(3u<<4)|(1u<<6)|(2u<<8)|(0u<<10)|(1u<<12)|(3u<<14)|(0u<<16)|(2u<<18);
  const unsigned bPack = (2u<<0)|(0u<<2)|(3u<<4)|(1u<<6)|(2u<<8)|(0u<<10)|(1u<<12)|(3u<<14)|(0u<<16)|(2u<<18);
  float lsum = 0.0f;
  const int y = y0 + w;
  if (fr < 10){
    const int od = fr;
    const int ai = (aPack >> (2 * od)) & 3;
    const int bi = (bPack >> (2 * od)) & 3;
    const bool xshift = (od & 1) == 0;
    const float bp = bpost[od];
#pragma unroll
    for (int i = 0; i < 4; ++i){
#pragma unroll
      for (int q = 0; q < 4; ++q){
        const int xo = i * 16 + g * 4 + q;
        const size_t gm = (size_t)b * 4096 + (size_t)y * 64 + xo;
        const f32x4 sa = S[gm];
        const bool nb = xshift ? (xo < 63) : (y < 63);
        const size_t ga = xshift ? (nb ? gm + 1 : gm) : (nb ? gm + 64 : gm);
        const f32x4 sbv = S[ga];
        const float sbf = nb ? sel4(sbv, bi) : 0.0f;
        const float flow = (sel4(sa, ai) - sbf) * 0.125f;
        const float dv = acc[i][q] + bp - flow;
        const float adv = fabsf(dv);
        lsum += (adv < 0.01f) ? (50.0f * dv * dv) : (adv - 0.005f);
      }
    }
  }
#pragma unroll
  for (int off = 32; off > 0; off >>= 1) lsum += __shfl_down(lsum, off);
  if (l == 0) ps[w] = lsum;
  __syncthreads();
  if (t == 0){
    float s = 0.0f;
#pragma unroll
    for (int i = 0; i < 8; ++i) s += ps[i];
    atomicAdd(out, s * (1.0f / 1310720.0f));
  }
}

// ---------------- launch ----------------
extern "C" void kernel_launch(void* const* d_in, const int* in_sizes, int n_in,
                              void* d_out, int out_size, void* d_ws, size_t ws_size,
                              hipStream_t stream){
  const float* feat  = (const float*)d_in[0];
  const float* depth = (const float*)d_in[1];
  const float* gts   = (const float*)d_in[2];
  const float* Watt  = (const float*)d_in[3];
  const float* batt  = (const float*)d_in[4];
  const float* Wpost = (const float*)d_in[5];
  const float* bpost = (const float*)d_in[6];
  float* out = (float*)d_out;
  char* ws = (char*)d_ws;

  unsigned short* adT = (unsigned short*)ws;                       // 16777216 B
  unsigned short* WT1 = (unsigned short*)(ws + 16777216);          // 294912 B
  unsigned short* WT2 = (unsigned short*)(ws + 16777216 + 294912); // 18432 B
  float*          S   = (float*)(ws + 16777216 + 294912 + 18432);  // 2097152 B

  k_weights<<<576, 256, 0, stream>>>(Watt, Wpost, WT1, WT2);
  k_gemm1<<<512, 256, 0, stream>>>(feat, WT1, batt, depth, adT);
  k_borders<<<2048, 256, 0, stream>>>(gts, S, out);
  k_gemm2<<<256, 512, 0, stream>>>(adT, WT2, bpost, (const f32x4*)S, out);
}